// Round 6
// baseline (154.405 us; speedup 1.0000x reference)
//
#include <hip/hip_runtime.h>
#include <hip/hip_bf16.h>
#include <stdint.h>

#define FH 45
#define FW 80
#define CIN 64
#define CF 64
#define NANCH 2784
#define BB 16
#define JP 80            // padded j dimension (75 real: 2 cls + 73 reg)
#define JN 75
#define MROW (FH * FW)         // 3600 rows per batch
#define SB ((MROW + 1) * JP)   // per-batch M stride in ELEMENTS (pad row unused)
#define ANB3 87                // anchors per k3 block (32*87 = 2784 exactly)
#define PLROW 44               // LDS words per plane row (176 B, 16B-aligned, bank-spread)
#define PLSZ (81 * PLROW)      // plane buffer words (row 80 = zero row for invalid)
#define PLBYTES 12800          // global bytes per y-plane (80 rows * 160 B)

static __device__ __forceinline__ uint32_t pkbf(float a, float b) {
    uint32_t lo = (uint32_t)__bfloat16_as_ushort(__float2bfloat16(a));
    uint32_t hi = (uint32_t)__bfloat16_as_ushort(__float2bfloat16(b));
    return lo | (hi << 16);
}

// ---------------- k1: V[y][ci][j] (f32), biasM[y][j], x-table (uint8) ----------------
__global__ __launch_bounds__(256) void k1_weights(
    const float* __restrict__ conv_w, const float* __restrict__ conv_b,
    const float* __restrict__ cls_w, const float* __restrict__ reg_w,
    const int* __restrict__ cut_xs, const uint8_t* __restrict__ invalid,
    float* __restrict__ V, float* __restrict__ biasM, uint8_t* __restrict__ xv) {
    int blk = blockIdx.x;
    int tid = threadIdx.x;
    if (blk >= 90) {
        int idx = (blk - 90) * 256 + tid;
        if (idx < NANCH * FH)
            xv[idx] = invalid[idx] ? (uint8_t)80 : (uint8_t)cut_xs[idx];
        return;
    }
    int y = blk >> 1;
    int j0 = (blk & 1) * 40;
    __shared__ float cw[CF * CIN];   // 16 KB
    __shared__ float wl[CF * 40];    // 10 KB
    __shared__ float cb[CF];
    for (int i = tid; i < CF * CIN; i += 256) cw[i] = conv_w[i];
    if (tid < CF) cb[tid] = conv_b[tid];
    for (int i = tid; i < CF * 40; i += 256) {
        int c = i / 40, jl = i % 40, j = j0 + jl;
        float v = 0.f;
        if (j < 2) v = cls_w[(c * FH + y) * 2 + j];
        else if (j < JN) v = reg_w[(c * FH + y) * 73 + (j - 2)];
        wl[i] = v;
    }
    __syncthreads();
    int ci = tid & 63;
    int jb = tid >> 6;               // 0..3
    float acc[10];
    #pragma unroll
    for (int k = 0; k < 10; ++k) acc[k] = 0.f;
    for (int c = 0; c < CF; ++c) {
        float a = cw[c * CIN + ci];
        #pragma unroll
        for (int k = 0; k < 10; ++k)
            acc[k] = fmaf(a, wl[c * 40 + jb + 4 * k], acc[k]);
    }
    #pragma unroll
    for (int k = 0; k < 10; ++k)
        V[y * (CIN * JP) + ci * JP + j0 + jb + 4 * k] = acc[k];
    if (tid < 40) {
        float s = 0.f;
        for (int c = 0; c < CF; ++c) s += cb[c] * wl[c * 40 + tid];
        biasM[y * JP + j0 + tid] = s;
    }
}

// ---------------- k2: M[b][(y*FW+x)][j] (bf16) = sum_ci x*V + biasM ----------------
// XCD-swizzled by b so slab b's dirty lines live in the L2 that k3 reads from.
__global__ __launch_bounds__(256) void k2_feat(
    const float* __restrict__ x, const float* __restrict__ V,
    const float* __restrict__ biasM, __hip_bfloat16* __restrict__ M) {
    int wg = blockIdx.x;
    int b = (wg % 8) * 2 + ((wg >> 3) & 1);
    int y = wg >> 4;                 // 0..44
    __shared__ float xl[CIN * FW];   // 20 KB
    __shared__ float vl[CIN * JP];   // 20 KB
    __shared__ float bl[JP];
    int tid = threadIdx.x;
    for (int t = tid; t < CIN * FW; t += 256) {
        int ci = t / FW, xc = t % FW;
        xl[t] = x[((b * CIN + ci) * FH + y) * FW + xc];
    }
    const float* vsrc = V + y * (CIN * JP);
    for (int t = tid; t < CIN * JP; t += 256) vl[t] = vsrc[t];
    if (tid < JP) bl[tid] = biasM[y * JP + tid];
    __syncthreads();
    if (tid < 200) {                  // 20 x-groups(4) x 10 j-groups(8)
        int tx = tid % 20;
        int tj = tid / 20;
        int x0 = tx * 4, jg0 = tj * 8;
        float acc[4][8];
        for (int xx = 0; xx < 4; ++xx)
            for (int jj = 0; jj < 8; ++jj)
                acc[xx][jj] = bl[jg0 + jj];
        for (int ci = 0; ci < CIN; ++ci) {
            float4 xvv = *reinterpret_cast<const float4*>(&xl[ci * FW + x0]);
            float4 v0 = *reinterpret_cast<const float4*>(&vl[ci * JP + jg0]);
            float4 v1 = *reinterpret_cast<const float4*>(&vl[ci * JP + jg0 + 4]);
            float xa[4] = {xvv.x, xvv.y, xvv.z, xvv.w};
            float va[8] = {v0.x, v0.y, v0.z, v0.w, v1.x, v1.y, v1.z, v1.w};
            for (int xx = 0; xx < 4; ++xx)
                for (int jj = 0; jj < 8; ++jj)
                    acc[xx][jj] = fmaf(xa[xx], va[jj], acc[xx][jj]);
        }
        __hip_bfloat16* mbase = M + (size_t)b * SB + ((size_t)y * FW) * JP;
        for (int xx = 0; xx < 4; ++xx) {
            uint32_t* row = (uint32_t*)(mbase + (size_t)(x0 + xx) * JP + jg0);
            uint4 pk;
            pk.x = pkbf(acc[xx][0], acc[xx][1]);
            pk.y = pkbf(acc[xx][2], acc[xx][3]);
            pk.z = pkbf(acc[xx][4], acc[xx][5]);
            pk.w = pkbf(acc[xx][6], acc[xx][7]);
            *reinterpret_cast<uint4*>(row) = pk;
        }
    }
}

// ---------------- k3: y-plane streaming gather (LDS double-buffered) ----------------
// block = (b, 87 anchors); 870 tasks = (anchor, jg of 8 j's); 800 stagers.
__global__ __launch_bounds__(896) void k3_gather(
    const __hip_bfloat16* __restrict__ M, const float* __restrict__ anchors,
    const float* __restrict__ cls_b, const float* __restrict__ reg_b,
    const uint8_t* __restrict__ xv, float* __restrict__ out) {
    __shared__ uint32_t pl[2 * PLSZ];      // 28.5 KB, two plane buffers
    __shared__ uint8_t sx[ANB3 * FH];      // 3.9 KB x-table [anchor][y]
    __shared__ float sbias[JN + 1];
    int tid = threadIdx.x;
    int wg = blockIdx.x;
    int b = (wg % 8) * 2 + ((wg >> 3) & 1);   // XCD q owns batches {2q,2q+1}
    int chunk = wg >> 4;                       // 0..31
    int n0 = chunk * ANB3;
    const char* slab = (const char*)(M + (size_t)b * SB);

    for (int i = tid; i < ANB3 * FH; i += 896) sx[i] = xv[n0 * FH + i];
    if (tid < JN) sbias[tid] = (tid < 2) ? cls_b[tid] : reg_b[tid - 2];
    // zero row x=80 of both buffers (invalid-mask target)
    if (tid < 2 * PLROW)
        pl[(tid < PLROW ? 0 : PLSZ) + 80 * PLROW + (tid % PLROW)] = 0u;
    // stage plane 0 into buffer 0
    int xr = tid / 10, w4 = tid % 10;
    if (tid < 800)
        *reinterpret_cast<uint4*>(&pl[xr * PLROW + w4 * 4]) =
            *reinterpret_cast<const uint4*>(slab + tid * 16);
    __syncthreads();

    int anc = tid / 10, jg = tid % 10;
    bool task = (tid < ANB3 * 10);
    const uint8_t* sxa = sx + anc * FH;
    float s[8];
    #pragma unroll
    for (int e = 0; e < 8; ++e) s[e] = 0.f;

    for (int y = 0; y < FH; ++y) {
        uint32_t cur = (uint32_t)(y & 1) * PLSZ;
        uint32_t nxt = PLSZ - cur;
        // issue next plane's global load first (latency hides under gather)
        uint4 g;
        bool stg = (y + 1 < FH) && (tid < 800);
        if (stg)
            g = *reinterpret_cast<const uint4*>(slab + (size_t)(y + 1) * PLBYTES + tid * 16);
        if (task) {
            int xcell = sxa[y];
            uint4 v = *reinterpret_cast<const uint4*>(&pl[cur + xcell * PLROW + jg * 4]);
            uint32_t u[4] = {v.x, v.y, v.z, v.w};
            #pragma unroll
            for (int p = 0; p < 4; ++p) {
                s[2 * p]     += __uint_as_float(u[p] << 16);
                s[2 * p + 1] += __uint_as_float(u[p] & 0xFFFF0000u);
            }
        }
        if (stg)
            *reinterpret_cast<uint4*>(&pl[nxt + xr * PLROW + w4 * 4]) = g;
        __syncthreads();   // next plane complete; current buffer free to overwrite
    }

    if (task) {
        int n = n0 + anc;
        float* dst = out + ((size_t)b * NANCH + n) * 77;
        const float* arow = anchors + (size_t)n * 77;
        int j0 = jg * 8;
        #pragma unroll
        for (int e = 0; e < 8; ++e) {
            int j = j0 + e;
            if (j < 2)       dst[j]     = s[e] + sbias[j];
            else if (j < JN) dst[j + 2] = s[e] + sbias[j] + arow[j + 2];
        }
        if (jg == 0) { dst[2] = arow[2]; dst[3] = arow[3]; }
    }
}

extern "C" void kernel_launch(void* const* d_in, const int* in_sizes, int n_in,
                              void* d_out, int out_size, void* d_ws, size_t ws_size,
                              hipStream_t stream) {
    const float* x       = (const float*)d_in[0];
    const float* conv_w  = (const float*)d_in[1];
    const float* conv_b  = (const float*)d_in[2];
    const float* cls_w   = (const float*)d_in[3];
    const float* cls_b   = (const float*)d_in[4];
    const float* reg_w   = (const float*)d_in[5];
    const float* reg_b   = (const float*)d_in[6];
    const float* anchors = (const float*)d_in[7];
    const int* cut_xs    = (const int*)d_in[8];
    const uint8_t* invalid = (const uint8_t*)d_in[9];
    float* out = (float*)d_out;

    float* V     = (float*)d_ws;                              // FH*CIN*JP f32
    float* biasM = V + FH * CIN * JP;                         // FH*JP f32
    __hip_bfloat16* M = (__hip_bfloat16*)(biasM + FH * JP);   // BB*SB bf16
    uint8_t* xv  = (uint8_t*)((char*)M + (size_t)BB * SB * sizeof(__hip_bfloat16));

    int n_xv_blocks = (NANCH * FH + 255) / 256;               // 490
    k1_weights<<<90 + n_xv_blocks, 256, 0, stream>>>(conv_w, conv_b, cls_w, reg_w,
                                                     cut_xs, invalid, V, biasM, xv);
    k2_feat<<<BB * FH, 256, 0, stream>>>(x, V, biasM, M);
    k3_gather<<<512, 896, 0, stream>>>(M, anchors, cls_b, reg_b, xv, out);
}